// Round 6
// baseline (13348.456 us; speedup 1.0000x reference)
//
#include <hip/hip_runtime.h>
#include <hip/hip_bf16.h>
#include <cstdint>

#define TB 16
#define TT 16384
#define TI 64
#define TH 128
#define TG 512  // 4*H

typedef _Float16 half2_t __attribute__((ext_vector_type(2)));

__device__ __forceinline__ float sigf(float z) {
    return 1.0f / (1.0f + __expf(-z));
}
__device__ __forceinline__ float tanhf_fast(float z) {
    return 2.0f / (1.0f + __expf(-2.0f * z)) - 1.0f;
}
__device__ __forceinline__ float4 ld4(const float* p) {
    return *reinterpret_cast<const float4*>(p);
}
__device__ __forceinline__ void fma4(float4& acc, const float4 w, const float4 h) {
    acc.x = fmaf(w.x, h.x, acc.x);
    acc.y = fmaf(w.y, h.y, acc.y);
    acc.z = fmaf(w.z, h.z, acc.z);
    acc.w = fmaf(w.w, h.w, acc.w);
}
__device__ __forceinline__ float hsum4(const float4 a) {
    return (a.x + a.y) + (a.z + a.w);
}
__device__ __forceinline__ void pin2(half2_t& v) {
    asm volatile("" : "+v"(v));
}

// ---------------------------------------------------------------------------
// gx = x @ W_ih^T + b_ih + b_hh
// ---------------------------------------------------------------------------
__global__ __launch_bounds__(256, 2) void gx_precompute(
    const float* __restrict__ x, const float* __restrict__ W_ih,
    const float* __restrict__ b_ih, const float* __restrict__ b_hh,
    float* __restrict__ gx)
{
    const int tid  = threadIdx.x;
    const int j    = tid & (TH - 1);
    const int pair = tid >> 7;
    const int row_a = pair * 2 * TH + j;
    const int row_b = row_a + TH;

    float4 ua[TI / 4], ub[TI / 4];
#pragma unroll
    for (int k4 = 0; k4 < TI / 4; ++k4) {
        ua[k4] = ld4(W_ih + (size_t)row_a * TI + k4 * 4);
        ub[k4] = ld4(W_ih + (size_t)row_b * TI + k4 * 4);
    }
    const float bias_a = b_ih[row_a] + b_hh[row_a];
    const float bias_b = b_ih[row_b] + b_hh[row_b];

    __shared__ __align__(16) float xs[2][TI];
    const int ROWS = 128;
    const size_t r0 = (size_t)blockIdx.x * ROWS;

    if (tid < TI / 4)
        *reinterpret_cast<float4*>(&xs[0][tid * 4]) = ld4(x + r0 * TI + tid * 4);
    __syncthreads();
    float4 xreg = make_float4(0.f, 0.f, 0.f, 0.f);
    if (tid < TI / 4) xreg = ld4(x + (r0 + 1) * TI + tid * 4);

#pragma unroll 1
    for (int rr = 0; rr < ROWS; ++rr) {
        const float* xrow = xs[rr & 1];
        float4 aa = make_float4(0.f, 0.f, 0.f, 0.f);
        float4 ab = make_float4(0.f, 0.f, 0.f, 0.f);
#pragma unroll
        for (int k4 = 0; k4 < TI / 4; ++k4) {
            const float4 x4 = *reinterpret_cast<const float4*>(&xrow[k4 * 4]);
            fma4(aa, ua[k4], x4);
            fma4(ab, ub[k4], x4);
        }
        if (tid < TI / 4) {
            if (rr + 1 < ROWS)
                *reinterpret_cast<float4*>(&xs[(rr + 1) & 1][tid * 4]) = xreg;
            if (rr + 2 < ROWS) xreg = ld4(x + (r0 + rr + 2) * TI + tid * 4);
        }
        float* grow = gx + (r0 + rr) * (size_t)TG;
        grow[row_a] = hsum4(aa) + bias_a;
        grow[row_b] = hsum4(ab) + bias_b;

        asm volatile("s_waitcnt lgkmcnt(0)" ::: "memory");
        __builtin_amdgcn_s_barrier();
    }
}

// ---------------------------------------------------------------------------
// Sequential LSTM scan, quad layout. One block per batch element, 512 thr.
// Thread (j = tid>>2, q = tid&3) holds the K-quarter q of all 4 gate rows
// {j, 128+j, 256+j, 384+j} as 64 packed half2. After 2 shfl_xor rounds each
// quad thread has all 4 full pre-activations -> update happens in-thread:
// no g_lds exchange, ONE barrier/step (h double-buffered in LDS).
// ---------------------------------------------------------------------------
__global__
__attribute__((amdgpu_flat_work_group_size(512, 512), amdgpu_waves_per_eu(2, 2)))
void lstm_scan_quad(
    const float* __restrict__ W_hh, const float* __restrict__ gx,
    float* __restrict__ y, float* __restrict__ hn, float* __restrict__ cn)
{
    const int b   = blockIdx.x;
    const int tid = threadIdx.x;
    const int j   = tid >> 2;   // channel 0..127
    const int q   = tid & 3;    // K-quarter / gate slot

    __shared__ __align__(16) half2_t h2[2][TH / 2];   // double-buffered h (fp16)

    // weights: rows s*128+j, cols q*32..q*32+31 -> 4 x 16 half2 = 64 VGPRs
    half2_t w[4][16];
#pragma unroll
    for (int s = 0; s < 4; ++s) {
        const float* wr = W_hh + (size_t)(s * TH + j) * TH + q * 32;
#pragma unroll
        for (int k4 = 0; k4 < 8; ++k4) {
            const float4 v = ld4(wr + k4 * 4);
            w[s][2 * k4]     = half2_t{(_Float16)v.x, (_Float16)v.y};
            w[s][2 * k4 + 1] = half2_t{(_Float16)v.z, (_Float16)v.w};
        }
    }
#pragma unroll
    for (int s = 0; s < 4; ++s)
#pragma unroll
        for (int k = 0; k < 16; ++k) pin2(w[s][k]);

    // gate-slot select masks for folding gx into partial sums exactly once
    const float sel0 = (q == 0) ? 1.f : 0.f;
    const float sel1 = (q == 1) ? 1.f : 0.f;
    const float sel2 = (q == 2) ? 1.f : 0.f;
    const float sel3 = (q == 3) ? 1.f : 0.f;

    if (tid < TH / 2) h2[0][tid] = half2_t{(_Float16)0.f, (_Float16)0.f};
    float c_state = 0.0f;
    float h_keep  = 0.0f;

    // gx stream for row q*128+j, prefetched 3 steps ahead
    const float* gp = gx + (size_t)b * TT * TG + (q * TH + j);
    float g_c  = gp[0];
    float g_n1 = gp[TG];
    float g_n2 = gp[2 * (size_t)TG];
    float* yp = y + (size_t)b * TT * TH;

    __syncthreads();

    int cur = 0;
#pragma unroll 1
    for (int t = 0; t < TT; ++t) {
        float g_n3 = 0.f;
        if (t + 3 < TT) g_n3 = gp[(size_t)(t + 3) * TG];

        // ---- read this thread's h K-quarter: 4 x b128 (2-way bank alias) ---
        const float4* hv4 = reinterpret_cast<const float4*>(&h2[cur][q * 16]);
        const float4 hA = hv4[0], hB = hv4[1], hC = hv4[2], hD = hv4[3];
        half2_t hh[16];
        hh[0]  = __builtin_bit_cast(half2_t, hA.x);
        hh[1]  = __builtin_bit_cast(half2_t, hA.y);
        hh[2]  = __builtin_bit_cast(half2_t, hA.z);
        hh[3]  = __builtin_bit_cast(half2_t, hA.w);
        hh[4]  = __builtin_bit_cast(half2_t, hB.x);
        hh[5]  = __builtin_bit_cast(half2_t, hB.y);
        hh[6]  = __builtin_bit_cast(half2_t, hB.z);
        hh[7]  = __builtin_bit_cast(half2_t, hB.w);
        hh[8]  = __builtin_bit_cast(half2_t, hC.x);
        hh[9]  = __builtin_bit_cast(half2_t, hC.y);
        hh[10] = __builtin_bit_cast(half2_t, hC.z);
        hh[11] = __builtin_bit_cast(half2_t, hC.w);
        hh[12] = __builtin_bit_cast(half2_t, hD.x);
        hh[13] = __builtin_bit_cast(half2_t, hD.y);
        hh[14] = __builtin_bit_cast(half2_t, hD.z);
        hh[15] = __builtin_bit_cast(half2_t, hD.w);

        // ---- 4 gate-row partials over this K-quarter (4 dot2 chains) ------
        float p0 = sel0 * g_c;
        float p1 = sel1 * g_c;
        float p2 = sel2 * g_c;
        float p3 = sel3 * g_c;
#pragma unroll
        for (int k = 0; k < 16; ++k) {
            p0 = __builtin_amdgcn_fdot2(w[0][k], hh[k], p0, false);
            p1 = __builtin_amdgcn_fdot2(w[1][k], hh[k], p1, false);
            p2 = __builtin_amdgcn_fdot2(w[2][k], hh[k], p2, false);
            p3 = __builtin_amdgcn_fdot2(w[3][k], hh[k], p3, false);
        }

        // ---- intra-quad reduce: every quad thread gets all 4 full sums ----
        p0 += __shfl_xor(p0, 1); p1 += __shfl_xor(p1, 1);
        p2 += __shfl_xor(p2, 1); p3 += __shfl_xor(p3, 1);
        p0 += __shfl_xor(p0, 2); p1 += __shfl_xor(p1, 2);
        p2 += __shfl_xor(p2, 2); p3 += __shfl_xor(p3, 2);

        // ---- gates + state update, fully in-thread -----------------------
        const float gi = sigf(p0);
        const float gf = sigf(p1);
        const float gg = tanhf_fast(p2);
        const float go = sigf(p3);
        c_state = fmaf(gf, c_state, gi * gg);
        h_keep  = go * tanhf_fast(c_state);

        const int nxt = cur ^ 1;
        if (q == 0)
            reinterpret_cast<_Float16*>(&h2[nxt][0])[j] = (_Float16)h_keep;
        if (q == 1)
            yp[(size_t)t * TH + j] = h_keep;

        g_c = g_n1; g_n1 = g_n2; g_n2 = g_n3;
        cur = nxt;

        asm volatile("s_waitcnt lgkmcnt(0)" ::: "memory");
        __builtin_amdgcn_s_barrier();
    }

    if (q == 2) hn[(size_t)b * TH + j] = h_keep;
    if (q == 3) cn[(size_t)b * TH + j] = c_state;
}

// ---------------------------------------------------------------------------
// Fallback scan (no workspace): f32, recomputes x-projection on the fly.
// ---------------------------------------------------------------------------
__global__ __launch_bounds__(512, 2) void lstm_scan_fused(
    const float* __restrict__ x, const float* __restrict__ W_ih,
    const float* __restrict__ W_hh, const float* __restrict__ b_ih,
    const float* __restrict__ b_hh,
    float* __restrict__ y, float* __restrict__ hn, float* __restrict__ cn)
{
    const int b    = blockIdx.x;
    const int tid  = threadIdx.x;
    const int j    = tid & (TH - 1);
    const int gate = tid >> 7;

    __shared__ __align__(16) float h_lds[TH];
    __shared__ __align__(16) float g_lds[TG];
    __shared__ __align__(16) float xs[2][TI];

    float4 w[TH / 4];
#pragma unroll
    for (int k4 = 0; k4 < TH / 4; ++k4)
        w[k4] = ld4(W_hh + (size_t)tid * TH + k4 * 4);
    float4 u[TI / 4];
#pragma unroll
    for (int k4 = 0; k4 < TI / 4; ++k4)
        u[k4] = ld4(W_ih + (size_t)tid * TI + k4 * 4);
    const float bias = b_ih[tid] + b_hh[tid];

    if (tid < TH) h_lds[tid] = 0.0f;
    float c_state = 0.0f;
    float h_keep  = 0.0f;

    float4 xreg = make_float4(0.f, 0.f, 0.f, 0.f);
    const float* xp = x + ((size_t)b * TT + 2) * TI;
    float* yp = y + (size_t)b * TT * TH;

    if (tid < TI / 4)
        *reinterpret_cast<float4*>(&xs[0][tid * 4]) =
            ld4(x + ((size_t)b * TT + 0) * TI + tid * 4);
    __syncthreads();
    if (tid < TI / 4)
        xreg = ld4(x + ((size_t)b * TT + 1) * TI + tid * 4);

#pragma unroll 1
    for (int t = 0; t < TT; ++t) {
        float4 acc = make_float4(0.f, 0.f, 0.f, 0.f);
#pragma unroll
        for (int k4 = 0; k4 < TH / 4; ++k4) {
            const float4 h4 = *reinterpret_cast<const float4*>(&h_lds[k4 * 4]);
            fma4(acc, w[k4], h4);
        }
        float p = hsum4(acc);
        {
            float4 fx = make_float4(0.f, 0.f, 0.f, 0.f);
            const float* xrow = xs[t & 1];
#pragma unroll
            for (int k4 = 0; k4 < TI / 4; ++k4) {
                const float4 x4 = *reinterpret_cast<const float4*>(&xrow[k4 * 4]);
                fma4(fx, u[k4], x4);
            }
            p += hsum4(fx) + bias;
        }

        const float act = (gate == 2) ? tanhf_fast(p) : sigf(p);
        g_lds[tid] = act;

        asm volatile("s_waitcnt lgkmcnt(0)" ::: "memory");
        __builtin_amdgcn_s_barrier();

        if (tid < TH) {
            const float gi = g_lds[j];
            const float gf = g_lds[TH + j];
            const float gg = g_lds[2 * TH + j];
            const float go = g_lds[3 * TH + j];
            c_state = fmaf(gf, c_state, gi * gg);
            h_keep  = go * tanhf_fast(c_state);
            h_lds[j] = h_keep;
            yp[(size_t)t * TH + j] = h_keep;
        }

        if (tid < TI / 4) {
            if (t + 1 < TT)
                *reinterpret_cast<float4*>(&xs[(t + 1) & 1][tid * 4]) = xreg;
            if (t + 2 < TT) xreg = ld4(xp + tid * 4);
        }
        xp += TI;

        asm volatile("s_waitcnt lgkmcnt(0)" ::: "memory");
        __builtin_amdgcn_s_barrier();
    }

    if (tid < TH) {
        hn[(size_t)b * TH + j] = h_keep;
        cn[(size_t)b * TH + j] = c_state;
    }
}

// ---------------------------------------------------------------------------
// BatchNorm over flattened [B*T, H] + LeakyReLU
// ---------------------------------------------------------------------------
__global__ void bn_zero(float* ws) { ws[threadIdx.x] = 0.0f; }

__global__ __launch_bounds__(256) void bn_stats(const float* __restrict__ y,
                                                float* __restrict__ ws)
{
    const int tid  = threadIdx.x;
    const int col4 = tid & 31;
    const int rg   = tid >> 5;
    const int NROW = TB * TT;
    float4 s = make_float4(0.f, 0.f, 0.f, 0.f);
    float4 q = make_float4(0.f, 0.f, 0.f, 0.f);
    for (int row = blockIdx.x * 8 + rg; row < NROW; row += gridDim.x * 8) {
        const float4 v = ld4(y + (size_t)row * TH + col4 * 4);
        s.x += v.x; s.y += v.y; s.z += v.z; s.w += v.w;
        q.x = fmaf(v.x, v.x, q.x); q.y = fmaf(v.y, v.y, q.y);
        q.z = fmaf(v.z, v.z, q.z); q.w = fmaf(v.w, v.w, q.w);
    }
    __shared__ float4 ls[256], lq[256];
    ls[tid] = s; lq[tid] = q;
    __syncthreads();
    if (tid < 32) {
        float4 S = ls[tid], Q = lq[tid];
        for (int g2 = 1; g2 < 8; ++g2) {
            const float4 a = ls[g2 * 32 + tid], b2 = lq[g2 * 32 + tid];
            S.x += a.x; S.y += a.y; S.z += a.z; S.w += a.w;
            Q.x += b2.x; Q.y += b2.y; Q.z += b2.z; Q.w += b2.w;
        }
        atomicAdd(&ws[tid * 4 + 0], S.x); atomicAdd(&ws[tid * 4 + 1], S.y);
        atomicAdd(&ws[tid * 4 + 2], S.z); atomicAdd(&ws[tid * 4 + 3], S.w);
        atomicAdd(&ws[TH + tid * 4 + 0], Q.x); atomicAdd(&ws[TH + tid * 4 + 1], Q.y);
        atomicAdd(&ws[TH + tid * 4 + 2], Q.z); atomicAdd(&ws[TH + tid * 4 + 3], Q.w);
    }
}

__global__ __launch_bounds__(256) void bn_apply(float* __restrict__ y,
                                                const float* __restrict__ ws,
                                                const float* __restrict__ gamma,
                                                const float* __restrict__ beta)
{
    const int tid  = threadIdx.x;
    const int col4 = tid & 31;
    const int rg   = tid >> 5;
    const int NROW = TB * TT;
    const float invN = 1.0f / (float)(TB * TT);

    const float4 sm = ld4(ws + col4 * 4);
    const float4 sq = ld4(ws + TH + col4 * 4);
    const float4 gm = ld4(gamma + col4 * 4);
    const float4 bt = ld4(beta + col4 * 4);
    float4 mean, scale, shift;
    mean.x = sm.x * invN; mean.y = sm.y * invN;
    mean.z = sm.z * invN; mean.w = sm.w * invN;
    scale.x = rsqrtf(fmaf(-mean.x, mean.x, sq.x * invN) + 1e-5f) * gm.x;
    scale.y = rsqrtf(fmaf(-mean.y, mean.y, sq.y * invN) + 1e-5f) * gm.y;
    scale.z = rsqrtf(fmaf(-mean.z, mean.z, sq.z * invN) + 1e-5f) * gm.z;
    scale.w = rsqrtf(fmaf(-mean.w, mean.w, sq.w * invN) + 1e-5f) * gm.w;
    shift.x = bt.x - mean.x * scale.x; shift.y = bt.y - mean.y * scale.y;
    shift.z = bt.z - mean.z * scale.z; shift.w = bt.w - mean.w * scale.w;

    for (int row = blockIdx.x * 8 + rg; row < NROW; row += gridDim.x * 8) {
        float* p = y + (size_t)row * TH + col4 * 4;
        float4 v = *reinterpret_cast<const float4*>(p);
        v.x = fmaf(v.x, scale.x, shift.x); v.y = fmaf(v.y, scale.y, shift.y);
        v.z = fmaf(v.z, scale.z, shift.z); v.w = fmaf(v.w, scale.w, shift.w);
        v.x = fmaxf(v.x, 0.01f * v.x); v.y = fmaxf(v.y, 0.01f * v.y);
        v.z = fmaxf(v.z, 0.01f * v.z); v.w = fmaxf(v.w, 0.01f * v.w);
        *reinterpret_cast<float4*>(p) = v;
    }
}

// ---------------------------------------------------------------------------
extern "C" void kernel_launch(void* const* d_in, const int* in_sizes, int n_in,
                              void* d_out, int out_size, void* d_ws, size_t ws_size,
                              hipStream_t stream)
{
    const float* x     = (const float*)d_in[0];
    const float* W_ih  = (const float*)d_in[1];
    const float* W_hh  = (const float*)d_in[2];
    const float* b_ih  = (const float*)d_in[3];
    const float* b_hh  = (const float*)d_in[4];
    const float* gamma = (const float*)d_in[5];
    const float* beta  = (const float*)d_in[6];

    float* y  = (float*)d_out;
    float* hn = y + (size_t)TB * TT * TH;
    float* cn = hn + TB * TH;

    float* ws_stats = (float*)d_ws;
    const size_t GX_BYTES = (size_t)TB * TT * TG * sizeof(float);
    const bool use_ws = ws_size >= GX_BYTES + 4096;

    bn_zero<<<1, 256, 0, stream>>>(ws_stats);

    if (use_ws) {
        float* gxbuf = (float*)((char*)d_ws + 4096);
        gx_precompute<<<2048, 256, 0, stream>>>(x, W_ih, b_ih, b_hh, gxbuf);
        lstm_scan_quad<<<TB, 512, 0, stream>>>(W_hh, gxbuf, y, hn, cn);
    } else {
        lstm_scan_fused<<<TB, 512, 0, stream>>>(x, W_ih, W_hh, b_ih, b_hh,
                                                y, hn, cn);
    }

    bn_stats<<<512, 256, 0, stream>>>(y, ws_stats);
    bn_apply<<<2048, 256, 0, stream>>>(y, ws_stats, gamma, beta);
}

// Round 7
// 12601.983 us; speedup vs baseline: 1.0592x; 1.0592x over previous
//
#include <hip/hip_runtime.h>
#include <hip/hip_bf16.h>
#include <cstdint>

#define TB 16
#define TT 16384
#define TI 64
#define TH 128
#define TG 512  // 4*H

typedef _Float16 half2_t __attribute__((ext_vector_type(2)));

__device__ __forceinline__ float sigf(float z) {
    return 1.0f / (1.0f + __expf(-z));
}
__device__ __forceinline__ float tanhf_fast(float z) {
    return 2.0f / (1.0f + __expf(-2.0f * z)) - 1.0f;
}
__device__ __forceinline__ float4 ld4(const float* p) {
    return *reinterpret_cast<const float4*>(p);
}
__device__ __forceinline__ void fma4(float4& acc, const float4 w, const float4 h) {
    acc.x = fmaf(w.x, h.x, acc.x);
    acc.y = fmaf(w.y, h.y, acc.y);
    acc.z = fmaf(w.z, h.z, acc.z);
    acc.w = fmaf(w.w, h.w, acc.w);
}
__device__ __forceinline__ float hsum4(const float4 a) {
    return (a.x + a.y) + (a.z + a.w);
}
__device__ __forceinline__ void pin2(half2_t& v) {
    asm volatile("" : "+v"(v));
}
// butterfly add within a quad of lanes via true DPP (VALU, no LDS pipe).
// ctrl 0xB1 = quad_perm[1,0,3,2] (xor 1), 0x4E = quad_perm[2,3,0,1] (xor 2)
__device__ __forceinline__ float dpp_add(float v, int ctrl) {
    int m = ctrl == 0xB1
        ? __builtin_amdgcn_update_dpp(0, __builtin_bit_cast(int, v), 0xB1, 0xF, 0xF, true)
        : __builtin_amdgcn_update_dpp(0, __builtin_bit_cast(int, v), 0x4E, 0xF, 0xF, true);
    return v + __builtin_bit_cast(float, m);
}

// ---------------------------------------------------------------------------
// gx = x @ W_ih^T + b_ih + b_hh
// ---------------------------------------------------------------------------
__global__ __launch_bounds__(256, 2) void gx_precompute(
    const float* __restrict__ x, const float* __restrict__ W_ih,
    const float* __restrict__ b_ih, const float* __restrict__ b_hh,
    float* __restrict__ gx)
{
    const int tid  = threadIdx.x;
    const int j    = tid & (TH - 1);
    const int pair = tid >> 7;
    const int row_a = pair * 2 * TH + j;
    const int row_b = row_a + TH;

    float4 ua[TI / 4], ub[TI / 4];
#pragma unroll
    for (int k4 = 0; k4 < TI / 4; ++k4) {
        ua[k4] = ld4(W_ih + (size_t)row_a * TI + k4 * 4);
        ub[k4] = ld4(W_ih + (size_t)row_b * TI + k4 * 4);
    }
    const float bias_a = b_ih[row_a] + b_hh[row_a];
    const float bias_b = b_ih[row_b] + b_hh[row_b];

    __shared__ __align__(16) float xs[2][TI];
    const int ROWS = 128;
    const size_t r0 = (size_t)blockIdx.x * ROWS;

    if (tid < TI / 4)
        *reinterpret_cast<float4*>(&xs[0][tid * 4]) = ld4(x + r0 * TI + tid * 4);
    __syncthreads();
    float4 xreg = make_float4(0.f, 0.f, 0.f, 0.f);
    if (tid < TI / 4) xreg = ld4(x + (r0 + 1) * TI + tid * 4);

#pragma unroll 1
    for (int rr = 0; rr < ROWS; ++rr) {
        const float* xrow = xs[rr & 1];
        float4 aa = make_float4(0.f, 0.f, 0.f, 0.f);
        float4 ab = make_float4(0.f, 0.f, 0.f, 0.f);
#pragma unroll
        for (int k4 = 0; k4 < TI / 4; ++k4) {
            const float4 x4 = *reinterpret_cast<const float4*>(&xrow[k4 * 4]);
            fma4(aa, ua[k4], x4);
            fma4(ab, ub[k4], x4);
        }
        if (tid < TI / 4) {
            if (rr + 1 < ROWS)
                *reinterpret_cast<float4*>(&xs[(rr + 1) & 1][tid * 4]) = xreg;
            if (rr + 2 < ROWS) xreg = ld4(x + (r0 + rr + 2) * TI + tid * 4);
        }
        float* grow = gx + (r0 + rr) * (size_t)TG;
        grow[row_a] = hsum4(aa) + bias_a;
        grow[row_b] = hsum4(ab) + bias_b;

        asm volatile("s_waitcnt lgkmcnt(0)" ::: "memory");
        __builtin_amdgcn_s_barrier();
    }
}

// ---------------------------------------------------------------------------
// Sequential LSTM scan, quad layout v6. One block per batch element, 512 thr.
// Thread (j = tid>>2, q = tid&3) holds K-quarter q of gate rows {s*128+j}.
// DPP quad butterfly reduce (VALU), pointer-bump addressing, 3-deep gx ring
// with slack rows (unconditional prefetch), ONE barrier/step (h dbuf in LDS).
// ---------------------------------------------------------------------------
__global__
__attribute__((amdgpu_flat_work_group_size(512, 512), amdgpu_waves_per_eu(2, 2)))
void lstm_scan_v6(
    const float* __restrict__ W_hh, const float* __restrict__ gx,
    float* __restrict__ y, float* __restrict__ hn, float* __restrict__ cn)
{
    const int b   = blockIdx.x;
    const int tid = threadIdx.x;
    const int j   = tid >> 2;   // channel 0..127
    const int q   = tid & 3;    // K-quarter / gate slot

    __shared__ __align__(16) half2_t h2[2][TH / 2];   // double-buffered h (fp16)

    // weights: rows s*128+j, cols q*32..q*32+31 -> 4 x 16 half2
    half2_t w[4][16];
#pragma unroll
    for (int s = 0; s < 4; ++s) {
        const float* wr = W_hh + (size_t)(s * TH + j) * TH + q * 32;
#pragma unroll
        for (int k4 = 0; k4 < 8; ++k4) {
            const float4 v = ld4(wr + k4 * 4);
            w[s][2 * k4]     = half2_t{(_Float16)v.x, (_Float16)v.y};
            w[s][2 * k4 + 1] = half2_t{(_Float16)v.z, (_Float16)v.w};
        }
    }
#pragma unroll
    for (int s = 0; s < 4; ++s)
#pragma unroll
        for (int k = 0; k < 16; ++k) pin2(w[s][k]);

    const float sel0 = (q == 0) ? 1.f : 0.f;
    const float sel1 = (q == 1) ? 1.f : 0.f;
    const float sel2 = (q == 2) ? 1.f : 0.f;
    const float sel3 = (q == 3) ? 1.f : 0.f;

    if (tid < TH / 2) h2[0][tid] = half2_t{(_Float16)0.f, (_Float16)0.f};
    float c_state = 0.0f;
    float h_keep  = 0.0f;

    // gx ring, 3 deep; slack rows after the buffer make loads unconditional
    const float* gpf = gx + (size_t)b * TT * TG + (q * TH + j);
    float g0 = gpf[0];
    float g1 = gpf[TG];
    float g2 = gpf[2 * TG];
    gpf += 3 * (size_t)TG;
    float* yp = y + (size_t)b * TT * TH + j;

    __syncthreads();

    auto step = [&](int CUR, int NXT) {
        const float gN = *gpf;          // prefetch t+3 (slack-backed)
        gpf += TG;

        // this thread's h K-quarter: 4 x b128 (2-way bank alias = free)
        const float4* hp = reinterpret_cast<const float4*>(&h2[CUR][q * 16]);
        const float4 hA = hp[0], hB = hp[1], hC = hp[2], hD = hp[3];
        half2_t hh[16];
        hh[0]  = __builtin_bit_cast(half2_t, hA.x);
        hh[1]  = __builtin_bit_cast(half2_t, hA.y);
        hh[2]  = __builtin_bit_cast(half2_t, hA.z);
        hh[3]  = __builtin_bit_cast(half2_t, hA.w);
        hh[4]  = __builtin_bit_cast(half2_t, hB.x);
        hh[5]  = __builtin_bit_cast(half2_t, hB.y);
        hh[6]  = __builtin_bit_cast(half2_t, hB.z);
        hh[7]  = __builtin_bit_cast(half2_t, hB.w);
        hh[8]  = __builtin_bit_cast(half2_t, hC.x);
        hh[9]  = __builtin_bit_cast(half2_t, hC.y);
        hh[10] = __builtin_bit_cast(half2_t, hC.z);
        hh[11] = __builtin_bit_cast(half2_t, hC.w);
        hh[12] = __builtin_bit_cast(half2_t, hD.x);
        hh[13] = __builtin_bit_cast(half2_t, hD.y);
        hh[14] = __builtin_bit_cast(half2_t, hD.z);
        hh[15] = __builtin_bit_cast(half2_t, hD.w);

        float p0 = sel0 * g0;
        float p1 = sel1 * g0;
        float p2 = sel2 * g0;
        float p3 = sel3 * g0;
#pragma unroll
        for (int k = 0; k < 16; ++k) {
            p0 = __builtin_amdgcn_fdot2(w[0][k], hh[k], p0, false);
            p1 = __builtin_amdgcn_fdot2(w[1][k], hh[k], p1, false);
            p2 = __builtin_amdgcn_fdot2(w[2][k], hh[k], p2, false);
            p3 = __builtin_amdgcn_fdot2(w[3][k], hh[k], p3, false);
        }

        // quad butterfly via DPP (pure VALU)
        p0 = dpp_add(p0, 0xB1); p1 = dpp_add(p1, 0xB1);
        p2 = dpp_add(p2, 0xB1); p3 = dpp_add(p3, 0xB1);
        p0 = dpp_add(p0, 0x4E); p1 = dpp_add(p1, 0x4E);
        p2 = dpp_add(p2, 0x4E); p3 = dpp_add(p3, 0x4E);

        const float gi = sigf(p0);
        const float gf = sigf(p1);
        const float gg = tanhf_fast(p2);
        const float go = sigf(p3);
        c_state = fmaf(gf, c_state, gi * gg);
        h_keep  = go * tanhf_fast(c_state);

        if (q == 0)
            reinterpret_cast<_Float16*>(&h2[NXT][0])[j] = (_Float16)h_keep;
        if (q == 1)
            *yp = h_keep;
        yp += TH;

        g0 = g1; g1 = g2; g2 = gN;

        asm volatile("s_waitcnt lgkmcnt(0)" ::: "memory");
        __builtin_amdgcn_s_barrier();
    };

#pragma unroll 1
    for (int t = 0; t < TT; t += 2) {
        step(0, 1);
        step(1, 0);
    }

    if (q == 2) hn[(size_t)b * TH + j] = h_keep;
    if (q == 3) cn[(size_t)b * TH + j] = c_state;
}

// ---------------------------------------------------------------------------
// Fallback scan (no workspace): f32, recomputes x-projection on the fly.
// ---------------------------------------------------------------------------
__global__ __launch_bounds__(512, 2) void lstm_scan_fused(
    const float* __restrict__ x, const float* __restrict__ W_ih,
    const float* __restrict__ W_hh, const float* __restrict__ b_ih,
    const float* __restrict__ b_hh,
    float* __restrict__ y, float* __restrict__ hn, float* __restrict__ cn)
{
    const int b    = blockIdx.x;
    const int tid  = threadIdx.x;
    const int j    = tid & (TH - 1);
    const int gate = tid >> 7;

    __shared__ __align__(16) float h_lds[TH];
    __shared__ __align__(16) float g_lds[TG];
    __shared__ __align__(16) float xs[2][TI];

    float4 w[TH / 4];
#pragma unroll
    for (int k4 = 0; k4 < TH / 4; ++k4)
        w[k4] = ld4(W_hh + (size_t)tid * TH + k4 * 4);
    float4 u[TI / 4];
#pragma unroll
    for (int k4 = 0; k4 < TI / 4; ++k4)
        u[k4] = ld4(W_ih + (size_t)tid * TI + k4 * 4);
    const float bias = b_ih[tid] + b_hh[tid];

    if (tid < TH) h_lds[tid] = 0.0f;
    float c_state = 0.0f;
    float h_keep  = 0.0f;

    float4 xreg = make_float4(0.f, 0.f, 0.f, 0.f);
    const float* xp = x + ((size_t)b * TT + 2) * TI;
    float* yp = y + (size_t)b * TT * TH;

    if (tid < TI / 4)
        *reinterpret_cast<float4*>(&xs[0][tid * 4]) =
            ld4(x + ((size_t)b * TT + 0) * TI + tid * 4);
    __syncthreads();
    if (tid < TI / 4)
        xreg = ld4(x + ((size_t)b * TT + 1) * TI + tid * 4);

#pragma unroll 1
    for (int t = 0; t < TT; ++t) {
        float4 acc = make_float4(0.f, 0.f, 0.f, 0.f);
#pragma unroll
        for (int k4 = 0; k4 < TH / 4; ++k4) {
            const float4 h4 = *reinterpret_cast<const float4*>(&h_lds[k4 * 4]);
            fma4(acc, w[k4], h4);
        }
        float p = hsum4(acc);
        {
            float4 fx = make_float4(0.f, 0.f, 0.f, 0.f);
            const float* xrow = xs[t & 1];
#pragma unroll
            for (int k4 = 0; k4 < TI / 4; ++k4) {
                const float4 x4 = *reinterpret_cast<const float4*>(&xrow[k4 * 4]);
                fma4(fx, u[k4], x4);
            }
            p += hsum4(fx) + bias;
        }

        const float act = (gate == 2) ? tanhf_fast(p) : sigf(p);
        g_lds[tid] = act;

        asm volatile("s_waitcnt lgkmcnt(0)" ::: "memory");
        __builtin_amdgcn_s_barrier();

        if (tid < TH) {
            const float gi = g_lds[j];
            const float gf = g_lds[TH + j];
            const float gg = g_lds[2 * TH + j];
            const float go = g_lds[3 * TH + j];
            c_state = fmaf(gf, c_state, gi * gg);
            h_keep  = go * tanhf_fast(c_state);
            h_lds[j] = h_keep;
            yp[(size_t)t * TH + j] = h_keep;
        }

        if (tid < TI / 4) {
            if (t + 1 < TT)
                *reinterpret_cast<float4*>(&xs[(t + 1) & 1][tid * 4]) = xreg;
            if (t + 2 < TT) xreg = ld4(xp + tid * 4);
        }
        xp += TI;

        asm volatile("s_waitcnt lgkmcnt(0)" ::: "memory");
        __builtin_amdgcn_s_barrier();
    }

    if (tid < TH) {
        hn[(size_t)b * TH + j] = h_keep;
        cn[(size_t)b * TH + j] = c_state;
    }
}

// ---------------------------------------------------------------------------
// BatchNorm over flattened [B*T, H] + LeakyReLU
// ---------------------------------------------------------------------------
__global__ void bn_zero(float* ws) { ws[threadIdx.x] = 0.0f; }

__global__ __launch_bounds__(256) void bn_stats(const float* __restrict__ y,
                                                float* __restrict__ ws)
{
    const int tid  = threadIdx.x;
    const int col4 = tid & 31;
    const int rg   = tid >> 5;
    const int NROW = TB * TT;
    float4 s = make_float4(0.f, 0.f, 0.f, 0.f);
    float4 q = make_float4(0.f, 0.f, 0.f, 0.f);
    for (int row = blockIdx.x * 8 + rg; row < NROW; row += gridDim.x * 8) {
        const float4 v = ld4(y + (size_t)row * TH + col4 * 4);
        s.x += v.x; s.y += v.y; s.z += v.z; s.w += v.w;
        q.x = fmaf(v.x, v.x, q.x); q.y = fmaf(v.y, v.y, q.y);
        q.z = fmaf(v.z, v.z, q.z); q.w = fmaf(v.w, v.w, q.w);
    }
    __shared__ float4 ls[256], lq[256];
    ls[tid] = s; lq[tid] = q;
    __syncthreads();
    if (tid < 32) {
        float4 S = ls[tid], Q = lq[tid];
        for (int g2 = 1; g2 < 8; ++g2) {
            const float4 a = ls[g2 * 32 + tid], b2 = lq[g2 * 32 + tid];
            S.x += a.x; S.y += a.y; S.z += a.z; S.w += a.w;
            Q.x += b2.x; Q.y += b2.y; Q.z += b2.z; Q.w += b2.w;
        }
        atomicAdd(&ws[tid * 4 + 0], S.x); atomicAdd(&ws[tid * 4 + 1], S.y);
        atomicAdd(&ws[tid * 4 + 2], S.z); atomicAdd(&ws[tid * 4 + 3], S.w);
        atomicAdd(&ws[TH + tid * 4 + 0], Q.x); atomicAdd(&ws[TH + tid * 4 + 1], Q.y);
        atomicAdd(&ws[TH + tid * 4 + 2], Q.z); atomicAdd(&ws[TH + tid * 4 + 3], Q.w);
    }
}

__global__ __launch_bounds__(256) void bn_apply(float* __restrict__ y,
                                                const float* __restrict__ ws,
                                                const float* __restrict__ gamma,
                                                const float* __restrict__ beta)
{
    const int tid  = threadIdx.x;
    const int col4 = tid & 31;
    const int rg   = tid >> 5;
    const int NROW = TB * TT;
    const float invN = 1.0f / (float)(TB * TT);

    const float4 sm = ld4(ws + col4 * 4);
    const float4 sq = ld4(ws + TH + col4 * 4);
    const float4 gm = ld4(gamma + col4 * 4);
    const float4 bt = ld4(beta + col4 * 4);
    float4 mean, scale, shift;
    mean.x = sm.x * invN; mean.y = sm.y * invN;
    mean.z = sm.z * invN; mean.w = sm.w * invN;
    scale.x = rsqrtf(fmaf(-mean.x, mean.x, sq.x * invN) + 1e-5f) * gm.x;
    scale.y = rsqrtf(fmaf(-mean.y, mean.y, sq.y * invN) + 1e-5f) * gm.y;
    scale.z = rsqrtf(fmaf(-mean.z, mean.z, sq.z * invN) + 1e-5f) * gm.z;
    scale.w = rsqrtf(fmaf(-mean.w, mean.w, sq.w * invN) + 1e-5f) * gm.w;
    shift.x = bt.x - mean.x * scale.x; shift.y = bt.y - mean.y * scale.y;
    shift.z = bt.z - mean.z * scale.z; shift.w = bt.w - mean.w * scale.w;

    for (int row = blockIdx.x * 8 + rg; row < NROW; row += gridDim.x * 8) {
        float* p = y + (size_t)row * TH + col4 * 4;
        float4 v = *reinterpret_cast<const float4*>(p);
        v.x = fmaf(v.x, scale.x, shift.x); v.y = fmaf(v.y, scale.y, shift.y);
        v.z = fmaf(v.z, scale.z, shift.z); v.w = fmaf(v.w, scale.w, shift.w);
        v.x = fmaxf(v.x, 0.01f * v.x); v.y = fmaxf(v.y, 0.01f * v.y);
        v.z = fmaxf(v.z, 0.01f * v.z); v.w = fmaxf(v.w, 0.01f * v.w);
        *reinterpret_cast<float4*>(p) = v;
    }
}

// ---------------------------------------------------------------------------
extern "C" void kernel_launch(void* const* d_in, const int* in_sizes, int n_in,
                              void* d_out, int out_size, void* d_ws, size_t ws_size,
                              hipStream_t stream)
{
    const float* x     = (const float*)d_in[0];
    const float* W_ih  = (const float*)d_in[1];
    const float* W_hh  = (const float*)d_in[2];
    const float* b_ih  = (const float*)d_in[3];
    const float* b_hh  = (const float*)d_in[4];
    const float* gamma = (const float*)d_in[5];
    const float* beta  = (const float*)d_in[6];

    float* y  = (float*)d_out;
    float* hn = y + (size_t)TB * TT * TH;
    float* cn = hn + TB * TH;

    float* ws_stats = (float*)d_ws;
    const size_t GX_BYTES = (size_t)TB * TT * TG * sizeof(float);
    // 4096 stats header + gx + 3 slack rows (unconditional ring prefetch)
    const bool use_ws = ws_size >= GX_BYTES + 4096 + 3 * TG * sizeof(float);

    bn_zero<<<1, 256, 0, stream>>>(ws_stats);

    if (use_ws) {
        float* gxbuf = (float*)((char*)d_ws + 4096);
        gx_precompute<<<2048, 256, 0, stream>>>(x, W_ih, b_ih, b_hh, gxbuf);
        lstm_scan_v6<<<TB, 512, 0, stream>>>(W_hh, gxbuf, y, hn, cn);
    } else {
        lstm_scan_fused<<<TB, 512, 0, stream>>>(x, W_ih, W_hh, b_ih, b_hh,
                                                y, hn, cn);
    }

    bn_stats<<<512, 256, 0, stream>>>(y, ws_stats);
    bn_apply<<<2048, 256, 0, stream>>>(y, ws_stats, gamma, beta);
}

// Round 8
// 10430.736 us; speedup vs baseline: 1.2797x; 1.2082x over previous
//
#include <hip/hip_runtime.h>
#include <hip/hip_bf16.h>
#include <cstdint>

#define TB 16
#define TT 16384
#define TI 64
#define TH 128
#define TG 512  // 4*H

typedef _Float16 f16x8 __attribute__((ext_vector_type(8)));
typedef float    f32x4 __attribute__((ext_vector_type(4)));

__device__ __forceinline__ float sigf(float z) {
    return 1.0f / (1.0f + __expf(-z));
}
__device__ __forceinline__ float tanhf_fast(float z) {
    return 2.0f / (1.0f + __expf(-2.0f * z)) - 1.0f;
}
__device__ __forceinline__ float4 ld4(const float* p) {
    return *reinterpret_cast<const float4*>(p);
}
__device__ __forceinline__ void fma4(float4& acc, const float4 w, const float4 h) {
    acc.x = fmaf(w.x, h.x, acc.x);
    acc.y = fmaf(w.y, h.y, acc.y);
    acc.z = fmaf(w.z, h.z, acc.z);
    acc.w = fmaf(w.w, h.w, acc.w);
}
__device__ __forceinline__ float hsum4(const float4 a) {
    return (a.x + a.y) + (a.z + a.w);
}

// ---------------------------------------------------------------------------
// gx = x @ W_ih^T + b_ih + b_hh
// ---------------------------------------------------------------------------
__global__ __launch_bounds__(256, 2) void gx_precompute(
    const float* __restrict__ x, const float* __restrict__ W_ih,
    const float* __restrict__ b_ih, const float* __restrict__ b_hh,
    float* __restrict__ gx)
{
    const int tid  = threadIdx.x;
    const int j    = tid & (TH - 1);
    const int pair = tid >> 7;
    const int row_a = pair * 2 * TH + j;
    const int row_b = row_a + TH;

    float4 ua[TI / 4], ub[TI / 4];
#pragma unroll
    for (int k4 = 0; k4 < TI / 4; ++k4) {
        ua[k4] = ld4(W_ih + (size_t)row_a * TI + k4 * 4);
        ub[k4] = ld4(W_ih + (size_t)row_b * TI + k4 * 4);
    }
    const float bias_a = b_ih[row_a] + b_hh[row_a];
    const float bias_b = b_ih[row_b] + b_hh[row_b];

    __shared__ __align__(16) float xs[2][TI];
    const int ROWS = 128;
    const size_t r0 = (size_t)blockIdx.x * ROWS;

    if (tid < TI / 4)
        *reinterpret_cast<float4*>(&xs[0][tid * 4]) = ld4(x + r0 * TI + tid * 4);
    __syncthreads();
    float4 xreg = make_float4(0.f, 0.f, 0.f, 0.f);
    if (tid < TI / 4) xreg = ld4(x + (r0 + 1) * TI + tid * 4);

#pragma unroll 1
    for (int rr = 0; rr < ROWS; ++rr) {
        const float* xrow = xs[rr & 1];
        float4 aa = make_float4(0.f, 0.f, 0.f, 0.f);
        float4 ab = make_float4(0.f, 0.f, 0.f, 0.f);
#pragma unroll
        for (int k4 = 0; k4 < TI / 4; ++k4) {
            const float4 x4 = *reinterpret_cast<const float4*>(&xrow[k4 * 4]);
            fma4(aa, ua[k4], x4);
            fma4(ab, ub[k4], x4);
        }
        if (tid < TI / 4) {
            if (rr + 1 < ROWS)
                *reinterpret_cast<float4*>(&xs[(rr + 1) & 1][tid * 4]) = xreg;
            if (rr + 2 < ROWS) xreg = ld4(x + (r0 + rr + 2) * TI + tid * 4);
        }
        float* grow = gx + (r0 + rr) * (size_t)TG;
        grow[row_a] = hsum4(aa) + bias_a;
        grow[row_b] = hsum4(ab) + bias_b;

        asm volatile("s_waitcnt lgkmcnt(0)" ::: "memory");
        __builtin_amdgcn_s_barrier();
    }
}

// ---------------------------------------------------------------------------
// MFMA LSTM scan. One block (8 waves) per batch element.
// Per step: G[1x512] = h[1x128] @ W_hh^T via mfma_f32_16x16x32_f16.
// A-trick: every lane loads the SAME h K-octet for its (lane>>4) group so all
// 16 A-rows are h -> every lane's acc[0] = G[16w + (lane&15)]. Wave w owns
// N-tiles {w, 8+w, 16+w, 24+w} = channels 16w..16w+15 for ALL 4 gates, so the
// c/h update is lane-local. h double-buffered in LDS (f16), 1 barrier/step.
// gx ring depth 4 with macro-constant slots (no register rotation).
// ---------------------------------------------------------------------------
__global__
__attribute__((amdgpu_flat_work_group_size(512, 512), amdgpu_waves_per_eu(2, 2)))
void lstm_scan_mfma(
    const float* __restrict__ W_hh, const float* __restrict__ gx,
    float* __restrict__ y, float* __restrict__ hn, float* __restrict__ cn)
{
    const int b    = blockIdx.x;
    const int tid  = threadIdx.x;
    const int w    = tid >> 6;        // wave 0..7
    const int lane = tid & 63;
    const int c    = lane & 15;       // channel-within-wave / N col
    const int oct  = lane >> 4;       // K octet selector

    __shared__ __align__(16) _Float16 h_lds[2][TH];

    // B fragments: frag (s,kt): 8 f16 = W_hh[row = s*128+16w+c][k = kt*32+oct*8 ..+7]
    f16x8 bf[4][4];
#pragma unroll
    for (int s = 0; s < 4; ++s) {
#pragma unroll
        for (int kt = 0; kt < 4; ++kt) {
            const float* wr =
                W_hh + (size_t)(s * TH + 16 * w + c) * TH + kt * 32 + oct * 8;
            const float4 lo = ld4(wr);
            const float4 hi = ld4(wr + 4);
            bf[s][kt] = f16x8{(_Float16)lo.x, (_Float16)lo.y, (_Float16)lo.z,
                              (_Float16)lo.w, (_Float16)hi.x, (_Float16)hi.y,
                              (_Float16)hi.z, (_Float16)hi.w};
        }
    }

    if (tid < TH) h_lds[0][tid] = (_Float16)0.f;

    float c_state = 0.0f;
    float h_keep  = 0.0f;

    // gx ring: [slot][gate], per-lane address gxp + t*512 + s*128
    const float* gxp = gx + (size_t)b * TT * TG + 16 * w + c;
    float gr[4][4];
#pragma unroll
    for (int sl = 0; sl < 4; ++sl) {
#pragma unroll
        for (int s = 0; s < 4; ++s)
            gr[sl][s] = gxp[(size_t)sl * TG + s * TH];
    }
    gxp += 4 * (size_t)TG;

    float* yp = y + (size_t)b * TT * TH + 16 * w + c;

    __syncthreads();

    const f32x4 kz = {0.f, 0.f, 0.f, 0.f};

#define STEP(SLOT, CUR, NXT)                                                   \
    {                                                                          \
        /* A fragments: uniform h octets (all 16 A-rows identical) */          \
        f16x8 a0 = *(const f16x8*)&h_lds[CUR][0 * 32 + oct * 8];               \
        f16x8 a1 = *(const f16x8*)&h_lds[CUR][1 * 32 + oct * 8];               \
        f16x8 a2 = *(const f16x8*)&h_lds[CUR][2 * 32 + oct * 8];               \
        f16x8 a3 = *(const f16x8*)&h_lds[CUR][3 * 32 + oct * 8];               \
        f32x4 q0 = __builtin_amdgcn_mfma_f32_16x16x32_f16(a0, bf[0][0], kz, 0, 0, 0); \
        f32x4 q1 = __builtin_amdgcn_mfma_f32_16x16x32_f16(a0, bf[1][0], kz, 0, 0, 0); \
        f32x4 q2 = __builtin_amdgcn_mfma_f32_16x16x32_f16(a0, bf[2][0], kz, 0, 0, 0); \
        f32x4 q3 = __builtin_amdgcn_mfma_f32_16x16x32_f16(a0, bf[3][0], kz, 0, 0, 0); \
        q0 = __builtin_amdgcn_mfma_f32_16x16x32_f16(a1, bf[0][1], q0, 0, 0, 0);\
        q1 = __builtin_amdgcn_mfma_f32_16x16x32_f16(a1, bf[1][1], q1, 0, 0, 0);\
        q2 = __builtin_amdgcn_mfma_f32_16x16x32_f16(a1, bf[2][1], q2, 0, 0, 0);\
        q3 = __builtin_amdgcn_mfma_f32_16x16x32_f16(a1, bf[3][1], q3, 0, 0, 0);\
        q0 = __builtin_amdgcn_mfma_f32_16x16x32_f16(a2, bf[0][2], q0, 0, 0, 0);\
        q1 = __builtin_amdgcn_mfma_f32_16x16x32_f16(a2, bf[1][2], q1, 0, 0, 0);\
        q2 = __builtin_amdgcn_mfma_f32_16x16x32_f16(a2, bf[2][2], q2, 0, 0, 0);\
        q3 = __builtin_amdgcn_mfma_f32_16x16x32_f16(a2, bf[3][2], q3, 0, 0, 0);\
        q0 = __builtin_amdgcn_mfma_f32_16x16x32_f16(a3, bf[0][3], q0, 0, 0, 0);\
        q1 = __builtin_amdgcn_mfma_f32_16x16x32_f16(a3, bf[1][3], q1, 0, 0, 0);\
        q2 = __builtin_amdgcn_mfma_f32_16x16x32_f16(a3, bf[2][3], q2, 0, 0, 0);\
        q3 = __builtin_amdgcn_mfma_f32_16x16x32_f16(a3, bf[3][3], q3, 0, 0, 0);\
        const float p0 = q0[0] + gr[SLOT][0];                                  \
        const float p1 = q1[0] + gr[SLOT][1];                                  \
        const float p2 = q2[0] + gr[SLOT][2];                                  \
        const float p3 = q3[0] + gr[SLOT][3];                                  \
        /* refill ring slot for t+4 (slack-backed past the end) */             \
        gr[SLOT][0] = gxp[0 * TH];                                             \
        gr[SLOT][1] = gxp[1 * TH];                                             \
        gr[SLOT][2] = gxp[2 * TH];                                             \
        gr[SLOT][3] = gxp[3 * TH];                                             \
        gxp += TG;                                                             \
        const float gi = sigf(p0);                                             \
        const float gf = sigf(p1);                                             \
        const float gg = tanhf_fast(p2);                                       \
        const float go = sigf(p3);                                             \
        c_state = fmaf(gf, c_state, gi * gg);                                  \
        h_keep  = go * tanhf_fast(c_state);                                    \
        if (lane < 16) {                                                       \
            h_lds[NXT][16 * w + c] = (_Float16)h_keep;                         \
            *yp = h_keep;                                                      \
        }                                                                      \
        yp += TH;                                                              \
        asm volatile("s_waitcnt lgkmcnt(0)" ::: "memory");                     \
        __builtin_amdgcn_s_barrier();                                          \
    }

#pragma unroll 1
    for (int t = 0; t < TT; t += 4) {
        STEP(0, 0, 1)
        STEP(1, 1, 0)
        STEP(2, 0, 1)
        STEP(3, 1, 0)
    }
#undef STEP

    if (lane < 16) {
        hn[(size_t)b * TH + 16 * w + c] = h_keep;
        cn[(size_t)b * TH + 16 * w + c] = c_state;
    }
}

// ---------------------------------------------------------------------------
// Fallback scan (no workspace): f32, recomputes x-projection on the fly.
// ---------------------------------------------------------------------------
__global__ __launch_bounds__(512, 2) void lstm_scan_fused(
    const float* __restrict__ x, const float* __restrict__ W_ih,
    const float* __restrict__ W_hh, const float* __restrict__ b_ih,
    const float* __restrict__ b_hh,
    float* __restrict__ y, float* __restrict__ hn, float* __restrict__ cn)
{
    const int b    = blockIdx.x;
    const int tid  = threadIdx.x;
    const int j    = tid & (TH - 1);
    const int gate = tid >> 7;

    __shared__ __align__(16) float h_lds[TH];
    __shared__ __align__(16) float g_lds[TG];
    __shared__ __align__(16) float xs[2][TI];

    float4 w[TH / 4];
#pragma unroll
    for (int k4 = 0; k4 < TH / 4; ++k4)
        w[k4] = ld4(W_hh + (size_t)tid * TH + k4 * 4);
    float4 u[TI / 4];
#pragma unroll
    for (int k4 = 0; k4 < TI / 4; ++k4)
        u[k4] = ld4(W_ih + (size_t)tid * TI + k4 * 4);
    const float bias = b_ih[tid] + b_hh[tid];

    if (tid < TH) h_lds[tid] = 0.0f;
    float c_state = 0.0f;
    float h_keep  = 0.0f;

    float4 xreg = make_float4(0.f, 0.f, 0.f, 0.f);
    const float* xp = x + ((size_t)b * TT + 2) * TI;
    float* yp = y + (size_t)b * TT * TH;

    if (tid < TI / 4)
        *reinterpret_cast<float4*>(&xs[0][tid * 4]) =
            ld4(x + ((size_t)b * TT + 0) * TI + tid * 4);
    __syncthreads();
    if (tid < TI / 4)
        xreg = ld4(x + ((size_t)b * TT + 1) * TI + tid * 4);

#pragma unroll 1
    for (int t = 0; t < TT; ++t) {
        float4 acc = make_float4(0.f, 0.f, 0.f, 0.f);
#pragma unroll
        for (int k4 = 0; k4 < TH / 4; ++k4) {
            const float4 h4 = *reinterpret_cast<const float4*>(&h_lds[k4 * 4]);
            fma4(acc, w[k4], h4);
        }
        float p = hsum4(acc);
        {
            float4 fx = make_float4(0.f, 0.f, 0.f, 0.f);
            const float* xrow = xs[t & 1];
#pragma unroll
            for (int k4 = 0; k4 < TI / 4; ++k4) {
                const float4 x4 = *reinterpret_cast<const float4*>(&xrow[k4 * 4]);
                fma4(fx, u[k4], x4);
            }
            p += hsum4(fx) + bias;
        }

        const float act = (gate == 2) ? tanhf_fast(p) : sigf(p);
        g_lds[tid] = act;

        asm volatile("s_waitcnt lgkmcnt(0)" ::: "memory");
        __builtin_amdgcn_s_barrier();

        if (tid < TH) {
            const float gi = g_lds[j];
            const float gf = g_lds[TH + j];
            const float gg = g_lds[2 * TH + j];
            const float go = g_lds[3 * TH + j];
            c_state = fmaf(gf, c_state, gi * gg);
            h_keep  = go * tanhf_fast(c_state);
            h_lds[j] = h_keep;
            yp[(size_t)t * TH + j] = h_keep;
        }

        if (tid < TI / 4) {
            if (t + 1 < TT)
                *reinterpret_cast<float4*>(&xs[(t + 1) & 1][tid * 4]) = xreg;
            if (t + 2 < TT) xreg = ld4(xp + tid * 4);
        }
        xp += TI;

        asm volatile("s_waitcnt lgkmcnt(0)" ::: "memory");
        __builtin_amdgcn_s_barrier();
    }

    if (tid < TH) {
        hn[(size_t)b * TH + j] = h_keep;
        cn[(size_t)b * TH + j] = c_state;
    }
}

// ---------------------------------------------------------------------------
// BatchNorm over flattened [B*T, H] + LeakyReLU
// ---------------------------------------------------------------------------
__global__ void bn_zero(float* ws) { ws[threadIdx.x] = 0.0f; }

__global__ __launch_bounds__(256) void bn_stats(const float* __restrict__ y,
                                                float* __restrict__ ws)
{
    const int tid  = threadIdx.x;
    const int col4 = tid & 31;
    const int rg   = tid >> 5;
    const int NROW = TB * TT;
    float4 s = make_float4(0.f, 0.f, 0.f, 0.f);
    float4 q = make_float4(0.f, 0.f, 0.f, 0.f);
    for (int row = blockIdx.x * 8 + rg; row < NROW; row += gridDim.x * 8) {
        const float4 v = ld4(y + (size_t)row * TH + col4 * 4);
        s.x += v.x; s.y += v.y; s.z += v.z; s.w += v.w;
        q.x = fmaf(v.x, v.x, q.x); q.y = fmaf(v.y, v.y, q.y);
        q.z = fmaf(v.z, v.z, q.z); q.w = fmaf(v.w, v.w, q.w);
    }
    __shared__ float4 ls[256], lq[256];
    ls[tid] = s; lq[tid] = q;
    __syncthreads();
    if (tid < 32) {
        float4 S = ls[tid], Q = lq[tid];
        for (int g2 = 1; g2 < 8; ++g2) {
            const float4 a = ls[g2 * 32 + tid], b2 = lq[g2 * 32 + tid];
            S.x += a.x; S.y += a.y; S.z += a.z; S.w += a.w;
            Q.x += b2.x; Q.y += b2.y; Q.z += b2.z; Q.w += b2.w;
        }
        atomicAdd(&ws[tid * 4 + 0], S.x); atomicAdd(&ws[tid * 4 + 1], S.y);
        atomicAdd(&ws[tid * 4 + 2], S.z); atomicAdd(&ws[tid * 4 + 3], S.w);
        atomicAdd(&ws[TH + tid * 4 + 0], Q.x); atomicAdd(&ws[TH + tid * 4 + 1], Q.y);
        atomicAdd(&ws[TH + tid * 4 + 2], Q.z); atomicAdd(&ws[TH + tid * 4 + 3], Q.w);
    }
}

__global__ __launch_bounds__(256) void bn_apply(float* __restrict__ y,
                                                const float* __restrict__ ws,
                                                const float* __restrict__ gamma,
                                                const float* __restrict__ beta)
{
    const int tid  = threadIdx.x;
    const int col4 = tid & 31;
    const int rg   = tid >> 5;
    const int NROW = TB * TT;
    const float invN = 1.0f / (float)(TB * TT);

    const float4 sm = ld4(ws + col4 * 4);
    const float4 sq = ld4(ws + TH + col4 * 4);
    const float4 gm = ld4(gamma + col4 * 4);
    const float4 bt = ld4(beta + col4 * 4);
    float4 mean, scale, shift;
    mean.x = sm.x * invN; mean.y = sm.y * invN;
    mean.z = sm.z * invN; mean.w = sm.w * invN;
    scale.x = rsqrtf(fmaf(-mean.x, mean.x, sq.x * invN) + 1e-5f) * gm.x;
    scale.y = rsqrtf(fmaf(-mean.y, mean.y, sq.y * invN) + 1e-5f) * gm.y;
    scale.z = rsqrtf(fmaf(-mean.z, mean.z, sq.z * invN) + 1e-5f) * gm.z;
    scale.w = rsqrtf(fmaf(-mean.w, mean.w, sq.w * invN) + 1e-5f) * gm.w;
    shift.x = bt.x - mean.x * scale.x; shift.y = bt.y - mean.y * scale.y;
    shift.z = bt.z - mean.z * scale.z; shift.w = bt.w - mean.w * scale.w;

    for (int row = blockIdx.x * 8 + rg; row < NROW; row += gridDim.x * 8) {
        float* p = y + (size_t)row * TH + col4 * 4;
        float4 v = *reinterpret_cast<const float4*>(p);
        v.x = fmaf(v.x, scale.x, shift.x); v.y = fmaf(v.y, scale.y, shift.y);
        v.z = fmaf(v.z, scale.z, shift.z); v.w = fmaf(v.w, scale.w, shift.w);
        v.x = fmaxf(v.x, 0.01f * v.x); v.y = fmaxf(v.y, 0.01f * v.y);
        v.z = fmaxf(v.z, 0.01f * v.z); v.w = fmaxf(v.w, 0.01f * v.w);
        *reinterpret_cast<float4*>(p) = v;
    }
}

// ---------------------------------------------------------------------------
extern "C" void kernel_launch(void* const* d_in, const int* in_sizes, int n_in,
                              void* d_out, int out_size, void* d_ws, size_t ws_size,
                              hipStream_t stream)
{
    const float* x     = (const float*)d_in[0];
    const float* W_ih  = (const float*)d_in[1];
    const float* W_hh  = (const float*)d_in[2];
    const float* b_ih  = (const float*)d_in[3];
    const float* b_hh  = (const float*)d_in[4];
    const float* gamma = (const float*)d_in[5];
    const float* beta  = (const float*)d_in[6];

    float* y  = (float*)d_out;
    float* hn = y + (size_t)TB * TT * TH;
    float* cn = hn + TB * TH;

    float* ws_stats = (float*)d_ws;
    const size_t GX_BYTES = (size_t)TB * TT * TG * sizeof(float);
    // 4096 stats header + gx + 4 slack rows (ring prefetch reads past end)
    const bool use_ws = ws_size >= GX_BYTES + 4096 + 4 * TG * sizeof(float);

    bn_zero<<<1, 256, 0, stream>>>(ws_stats);

    if (use_ws) {
        float* gxbuf = (float*)((char*)d_ws + 4096);
        gx_precompute<<<2048, 256, 0, stream>>>(x, W_ih, b_ih, b_hh, gxbuf);
        lstm_scan_mfma<<<TB, 512, 0, stream>>>(W_hh, gxbuf, y, hn, cn);
    } else {
        lstm_scan_fused<<<TB, 512, 0, stream>>>(x, W_ih, W_hh, b_ih, b_hh,
                                                y, hn, cn);
    }

    bn_stats<<<512, 256, 0, stream>>>(y, ws_stats);
    bn_apply<<<2048, 256, 0, stream>>>(y, ws_stats, gamma, beta);
}